// Round 6
// baseline (1325.590 us; speedup 1.0000x reference)
//
#include <hip/hip_runtime.h>
#include <hip/hip_bf16.h>

#define NN 100000
#define EE 1600000
#define DOUT 40
#define LN_EPS 1e-5f
#define NB 391  // (NN+255)/256

// ---------------------------------------------------------------- bf16 helpers (RNE pack)
__device__ __forceinline__ float blo(unsigned u) { return __uint_as_float(u << 16); }
__device__ __forceinline__ float bhi(unsigned u) { return __uint_as_float(u & 0xffff0000u); }
__device__ __forceinline__ unsigned bpack(float lo, float hi) {
    unsigned a = __float_as_uint(lo);
    unsigned b = __float_as_uint(hi);
    a = (a + 0x7fffu + ((a >> 16) & 1u)) >> 16;
    b = (b + 0x7fffu + ((b >> 16) & 1u)) & 0xffff0000u;
    return (a & 0xffffu) | b;
}

// ---------------------------------------------------------------- CSR build
__global__ void hist_k(const int* __restrict__ dst, int* __restrict__ degI) {
    int e = blockIdx.x * 256 + threadIdx.x;
    if (e < EE) atomicAdd(&degI[dst[e]], 1);
}

__global__ void dinv_k(const int* __restrict__ degI, float* __restrict__ dinv) {
    int n = blockIdx.x * 256 + threadIdx.x;
    if (n < NN) dinv[n] = rsqrtf((float)degI[n] + 1.0f);
}

__global__ void scan1_k(const int* __restrict__ degI, int* __restrict__ cursor,
                        int* __restrict__ bsum) {
    __shared__ int s[256];
    int tid = threadIdx.x;
    int i = blockIdx.x * 256 + tid;
    int v = (i < NN) ? degI[i] : 0;
    s[tid] = v;
    __syncthreads();
    for (int off = 1; off < 256; off <<= 1) {
        int t = (tid >= off) ? s[tid - off] : 0;
        __syncthreads();
        s[tid] += t;
        __syncthreads();
    }
    if (i < NN) cursor[i] = s[tid] - v;
    if (tid == 255) bsum[blockIdx.x] = s[255];
}

__global__ void scan2_k(int* __restrict__ bsum) {
    __shared__ int s[512];
    int tid = threadIdx.x;
    int v = (tid < NB) ? bsum[tid] : 0;
    s[tid] = v;
    __syncthreads();
    for (int off = 1; off < 512; off <<= 1) {
        int t = (tid >= off) ? s[tid - off] : 0;
        __syncthreads();
        s[tid] += t;
        __syncthreads();
    }
    if (tid < NB) bsum[tid] = s[tid] - v;
}

__global__ void scan3_k(int* __restrict__ cursor, const int* __restrict__ bsum) {
    int i = blockIdx.x * 256 + threadIdx.x;
    if (i < NN) cursor[i] += bsum[blockIdx.x];
}

__global__ void reorder_k(const int* __restrict__ src, const int* __restrict__ dst,
                          int* __restrict__ cursor, int* __restrict__ csrSrc) {
    int e = blockIdx.x * 256 + threadIdx.x;
    if (e < EE) {
        int pos = atomicAdd(&cursor[dst[e]], 1);
        csrSrc[pos] = src[e];
    }
}

// ---------------------------------------------------------------- GEMM  [N,K]@[K,64] -> H' = (xW)*dinv, bf16 packed
template <int K>
__global__ __launch_bounds__(256, 4) void gemm_k(const float* __restrict__ X,
                                                 const float* __restrict__ W,
                                                 const float* __restrict__ dinv,
                                                 unsigned* __restrict__ H) {
    __shared__ float sW[K * 64];
    int tid = threadIdx.x;
    for (int i = tid; i < K * 64; i += 256) sW[i] = W[i];
    __syncthreads();
    int w = tid >> 6, lane = tid & 63;
    for (int base = blockIdx.x * 4; base < NN; base += gridDim.x * 4) {
        int node = base + w;
        if (node < NN) {
            float xv0 = X[(long)node * K + lane];
            float xv1 = (K == 128) ? X[(long)node * K + 64 + lane] : 0.f;
            float acc = 0.f;
#pragma unroll
            for (int k = 0; k < 64; ++k) {
                float xk = __shfl(xv0, k);
                acc = fmaf(xk, sW[k * 64 + lane], acc);
            }
            if (K == 128) {
#pragma unroll
                for (int k = 0; k < 64; ++k) {
                    float xk = __shfl(xv1, k);
                    acc = fmaf(xk, sW[(64 + k) * 64 + lane], acc);
                }
            }
            acc *= dinv[node];
            float v0 = __shfl(acc, (lane & 31) * 2);
            float v1 = __shfl(acc, (lane & 31) * 2 + 1);
            if (lane < 32) H[node * 32 + lane] = bpack(v0, v1);
        }
    }
}

// ---------------------------------------------------------------- aggregate + bias + relu + optional LN
// R3-proven shape: wave per node; lane = g*16+f, g = edge slot (0..3),
// f = feature-quad (0..15); each lane reads uint2 (4 bf16, 8 B) -> 128 B/edge.
// 2-deep unroll => 8 outstanding gathers/wave. All state in named scalars.
__global__ __launch_bounds__(256, 4) void agg_k(
        const int* __restrict__ cursor, const int* __restrict__ degI,
        const int* __restrict__ csrSrc, const float* __restrict__ dinv,
        const uint2* __restrict__ H2, const float4* __restrict__ bias4,
        const float4* __restrict__ g4, const float4* __restrict__ beta4,
        float4* __restrict__ OUT4, int doLN) {
    int tid = threadIdx.x;
    int w = tid >> 6, lane = tid & 63;
    int g = lane >> 4;   // edge slot 0..3
    int f = lane & 15;   // feature-quad index
    int node = blockIdx.x * 4 + w;  // grid exactly NN/4
    int end = cursor[node];
    int start = end - degI[node];
    float ax = 0.f, ay = 0.f, az = 0.f, aw = 0.f;
    float bx = 0.f, by = 0.f, bz = 0.f, bw = 0.f;
    int e = start + g;
    for (; e + 4 < end; e += 8) {
        int s0 = csrSrc[e];
        int s1 = csrSrc[e + 4];
        uint2 q0 = H2[(long)s0 * 16 + f];
        uint2 q1 = H2[(long)s1 * 16 + f];
        ax += blo(q0.x); ay += bhi(q0.x); az += blo(q0.y); aw += bhi(q0.y);
        bx += blo(q1.x); by += bhi(q1.x); bz += blo(q1.y); bw += bhi(q1.y);
    }
    if (e < end) {
        uint2 q0 = H2[(long)csrSrc[e] * 16 + f];
        ax += blo(q0.x); ay += bhi(q0.x); az += blo(q0.y); aw += bhi(q0.y);
    }
    ax += bx; ay += by; az += bz; aw += bw;
    // reduce the 4 edge slots (xor on g bits 4,5)
    ax += __shfl_xor(ax, 16); ay += __shfl_xor(ay, 16);
    az += __shfl_xor(az, 16); aw += __shfl_xor(aw, 16);
    ax += __shfl_xor(ax, 32); ay += __shfl_xor(ay, 32);
    az += __shfl_xor(az, 32); aw += __shfl_xor(aw, 32);
    float di = dinv[node];
    uint2 qs = H2[(long)node * 16 + f];
    float4 bb = bias4[f];
    float vx = fmaxf((ax + blo(qs.x)) * di + bb.x, 0.f);
    float vy = fmaxf((ay + bhi(qs.x)) * di + bb.y, 0.f);
    float vz = fmaxf((az + blo(qs.y)) * di + bb.z, 0.f);
    float vw = fmaxf((aw + bhi(qs.y)) * di + bb.w, 0.f);
    if (doLN) {
        float s = vx + vy + vz + vw;
        s += __shfl_xor(s, 1); s += __shfl_xor(s, 2);
        s += __shfl_xor(s, 4); s += __shfl_xor(s, 8);
        float mu = s * (1.f / 64.f);
        vx -= mu; vy -= mu; vz -= mu; vw -= mu;
        float vs = vx * vx + vy * vy + vz * vz + vw * vw;
        vs += __shfl_xor(vs, 1); vs += __shfl_xor(vs, 2);
        vs += __shfl_xor(vs, 4); vs += __shfl_xor(vs, 8);
        float inv = rsqrtf(vs * (1.f / 64.f) + LN_EPS);
        float4 gg = g4[f];
        float4 tt = beta4[f];
        vx = vx * inv * gg.x + tt.x;
        vy = vy * inv * gg.y + tt.y;
        vz = vz * inv * gg.z + tt.z;
        vw = vw * inv * gg.w + tt.w;
    }
    if (g == 0) OUT4[(long)node * 16 + f] = make_float4(vx, vy, vz, vw);
}

// ---------------------------------------------------------------- dense MLP head: [N,64] -> 64 -> 40
__global__ __launch_bounds__(256, 4) void mlp_k(const float* __restrict__ Hin,
                                                const float* __restrict__ W0,
                                                const float* __restrict__ b0,
                                                const float* __restrict__ W1,
                                                const float* __restrict__ b1,
                                                float* __restrict__ OUT) {
    __shared__ float sW0[64 * 64];
    __shared__ float sW1[64 * DOUT];
    int tid = threadIdx.x;
    for (int i = tid; i < 64 * 64; i += 256) sW0[i] = W0[i];
    for (int i = tid; i < 64 * DOUT; i += 256) sW1[i] = W1[i];
    __syncthreads();
    int w = tid >> 6, lane = tid & 63;
    for (int node = blockIdx.x * 4 + w; node < NN; node += gridDim.x * 4) {
        float hv = Hin[(long)node * 64 + lane];
        float t = b0[lane];
#pragma unroll
        for (int k = 0; k < 64; ++k) t = fmaf(__shfl(hv, k), sW0[k * 64 + lane], t);
        int li = (lane < DOUT) ? lane : 0;
        float o = b1[li];
#pragma unroll
        for (int k = 0; k < 64; ++k) o = fmaf(__shfl(t, k), sW1[k * DOUT + li], o);
        if (lane < DOUT) OUT[(long)node * DOUT + lane] = o;
    }
}

// ----------------------------------------------------------------
extern "C" void kernel_launch(void* const* d_in, const int* in_sizes, int n_in,
                              void* d_out, int out_size, void* d_ws, size_t ws_size,
                              hipStream_t stream) {
    const float* x    = (const float*)d_in[0];
    const int*   ei   = (const int*)d_in[1];
    const int*   srcI = ei;
    const int*   dstI = ei + EE;
    const float* W0   = (const float*)d_in[2];
    const float* b0   = (const float*)d_in[3];
    const float* W1   = (const float*)d_in[4];
    const float* b1   = (const float*)d_in[5];
    const float* W2   = (const float*)d_in[6];
    const float* b2   = (const float*)d_in[7];
    const float* ln0g = (const float*)d_in[8];
    const float* ln0b = (const float*)d_in[9];
    const float* ln1g = (const float*)d_in[10];
    const float* ln1b = (const float*)d_in[11];
    const float* mpW0 = (const float*)d_in[12];
    const float* mpb0 = (const float*)d_in[13];
    const float* mpW1 = (const float*)d_in[14];
    const float* mpb1 = (const float*)d_in[15];
    float* out = (float*)d_out;

    char* ws = (char*)d_ws;
    float*    dinv   = (float*)   (ws + 0);
    int*      degI   = (int*)     (ws + 512l * 1024);
    int*      cursor = (int*)     (ws + 1024l * 1024);
    int*      bsum   = (int*)     (ws + 1536l * 1024);
    int*      csrSrc = (int*)     (ws + 2048l * 1024);          // 6.4 MB
    unsigned* bufA   = (unsigned*)(ws + 9l * 1024 * 1024);      // bf16 H'  12.8 MB
    float*    bufB   = (float*)   (ws + 23l * 1024 * 1024);     // f32 hidden 25.6 MB

    const int edgeBlocks = (EE + 255) / 256;
    const int aggBlocks  = NN / 4;  // 25000 exact

    hipMemsetAsync(degI, 0, NN * sizeof(int), stream);
    hist_k<<<edgeBlocks, 256, 0, stream>>>(dstI, degI);
    dinv_k<<<NB, 256, 0, stream>>>(degI, dinv);
    scan1_k<<<NB, 256, 0, stream>>>(degI, cursor, bsum);
    scan2_k<<<1, 512, 0, stream>>>(bsum);
    scan3_k<<<NB, 256, 0, stream>>>(cursor, bsum);
    reorder_k<<<edgeBlocks, 256, 0, stream>>>(srcI, dstI, cursor, csrSrc);

    // layer 0
    gemm_k<128><<<2048, 256, 0, stream>>>(x, W0, dinv, bufA);
    agg_k<<<aggBlocks, 256, 0, stream>>>(cursor, degI, csrSrc, dinv, (const uint2*)bufA,
                                         (const float4*)b0, (const float4*)ln0g,
                                         (const float4*)ln0b, (float4*)bufB, 1);
    // layer 1
    gemm_k<64><<<2048, 256, 0, stream>>>(bufB, W1, dinv, bufA);
    agg_k<<<aggBlocks, 256, 0, stream>>>(cursor, degI, csrSrc, dinv, (const uint2*)bufA,
                                         (const float4*)b1, (const float4*)ln1g,
                                         (const float4*)ln1b, (float4*)bufB, 1);
    // layer 2 (no LN) then dense MLP head
    gemm_k<64><<<2048, 256, 0, stream>>>(bufB, W2, dinv, bufA);
    agg_k<<<aggBlocks, 256, 0, stream>>>(cursor, degI, csrSrc, dinv, (const uint2*)bufA,
                                         (const float4*)b2, (const float4*)ln0g,
                                         (const float4*)ln0b, (float4*)bufB, 0);
    mlp_k<<<2048, 256, 0, stream>>>(bufB, mpW0, mpb0, mpW1, mpb1, out);
}

// Round 7
// 974.475 us; speedup vs baseline: 1.3603x; 1.3603x over previous
//
#include <hip/hip_runtime.h>
#include <hip/hip_bf16.h>

#define NN 100000
#define EE 1600000
#define DOUT 40
#define LN_EPS 1e-5f
#define NB 391  // (NN+255)/256

// ---------------------------------------------------------------- bf16 helpers (RNE pack)
__device__ __forceinline__ float blo(unsigned u) { return __uint_as_float(u << 16); }
__device__ __forceinline__ float bhi(unsigned u) { return __uint_as_float(u & 0xffff0000u); }
__device__ __forceinline__ unsigned bpack(float lo, float hi) {
    unsigned a = __float_as_uint(lo);
    unsigned b = __float_as_uint(hi);
    a = (a + 0x7fffu + ((a >> 16) & 1u)) >> 16;
    b = (b + 0x7fffu + ((b >> 16) & 1u)) & 0xffff0000u;
    return (a & 0xffffu) | b;
}

// ---------------------------------------------------------------- CSR build
__global__ void hist_k(const int* __restrict__ dst, int* __restrict__ degI) {
    int e = blockIdx.x * 256 + threadIdx.x;
    if (e < EE) atomicAdd(&degI[dst[e]], 1);
}

__global__ void dinv_k(const int* __restrict__ degI, float* __restrict__ dinv) {
    int n = blockIdx.x * 256 + threadIdx.x;
    if (n < NN) dinv[n] = rsqrtf((float)degI[n] + 1.0f);
}

__global__ void scan1_k(const int* __restrict__ degI, int* __restrict__ cursor,
                        int* __restrict__ bsum) {
    __shared__ int s[256];
    int tid = threadIdx.x;
    int i = blockIdx.x * 256 + tid;
    int v = (i < NN) ? degI[i] : 0;
    s[tid] = v;
    __syncthreads();
    for (int off = 1; off < 256; off <<= 1) {
        int t = (tid >= off) ? s[tid - off] : 0;
        __syncthreads();
        s[tid] += t;
        __syncthreads();
    }
    if (i < NN) cursor[i] = s[tid] - v;
    if (tid == 255) bsum[blockIdx.x] = s[255];
}

__global__ void scan2_k(int* __restrict__ bsum) {
    __shared__ int s[512];
    int tid = threadIdx.x;
    int v = (tid < NB) ? bsum[tid] : 0;
    s[tid] = v;
    __syncthreads();
    for (int off = 1; off < 512; off <<= 1) {
        int t = (tid >= off) ? s[tid - off] : 0;
        __syncthreads();
        s[tid] += t;
        __syncthreads();
    }
    if (tid < NB) bsum[tid] = s[tid] - v;
}

__global__ void scan3_k(int* __restrict__ cursor, const int* __restrict__ bsum) {
    int i = blockIdx.x * 256 + threadIdx.x;
    if (i < NN) cursor[i] += bsum[blockIdx.x];
}

__global__ void reorder_k(const int* __restrict__ src, const int* __restrict__ dst,
                          int* __restrict__ cursor, int* __restrict__ csrSrc) {
    int e = blockIdx.x * 256 + threadIdx.x;
    if (e < EE) {
        int pos = atomicAdd(&cursor[dst[e]], 1);
        csrSrc[pos] = src[e];
    }
}

// ---------------------------------------------------------------- GEMM  [N,K]@[K,64] -> H' = (xW)*dinv, bf16 packed
template <int K>
__global__ __launch_bounds__(256, 4) void gemm_k(const float* __restrict__ X,
                                                 const float* __restrict__ W,
                                                 const float* __restrict__ dinv,
                                                 unsigned* __restrict__ H) {
    __shared__ float sW[K * 64];
    int tid = threadIdx.x;
    for (int i = tid; i < K * 64; i += 256) sW[i] = W[i];
    __syncthreads();
    int w = tid >> 6, lane = tid & 63;
    for (int base = blockIdx.x * 4; base < NN; base += gridDim.x * 4) {
        int node = base + w;
        if (node < NN) {
            float xv0 = X[(long)node * K + lane];
            float xv1 = (K == 128) ? X[(long)node * K + 64 + lane] : 0.f;
            float acc = 0.f;
#pragma unroll
            for (int k = 0; k < 64; ++k) {
                float xk = __shfl(xv0, k);
                acc = fmaf(xk, sW[k * 64 + lane], acc);
            }
            if (K == 128) {
#pragma unroll
                for (int k = 0; k < 64; ++k) {
                    float xk = __shfl(xv1, k);
                    acc = fmaf(xk, sW[(64 + k) * 64 + lane], acc);
                }
            }
            acc *= dinv[node];
            float v0 = __shfl(acc, (lane & 31) * 2);
            float v1 = __shfl(acc, (lane & 31) * 2 + 1);
            if (lane < 32) H[node * 32 + lane] = bpack(v0, v1);
        }
    }
}

// ---------------------------------------------------------------- aggregate + bias + relu + optional LN
// One-shot grid (clean-measured shape): wave per node; lane = g*16+f,
// g = edge slot (0..3), f = feature-quad; lane reads uint2 (4 bf16) -> 128 B/edge.
__global__ __launch_bounds__(256, 4) void agg_k(
        const int* __restrict__ cursor, const int* __restrict__ degI,
        const int* __restrict__ csrSrc, const float* __restrict__ dinv,
        const uint2* __restrict__ H2, const float4* __restrict__ bias4,
        const float4* __restrict__ g4, const float4* __restrict__ beta4,
        float4* __restrict__ OUT4, int doLN) {
    int tid = threadIdx.x;
    int w = tid >> 6, lane = tid & 63;
    int g = lane >> 4;   // edge slot 0..3
    int f = lane & 15;   // feature-quad index
    int node = blockIdx.x * 4 + w;  // grid exactly NN/4
    int end = cursor[node];
    int start = end - degI[node];
    float ax = 0.f, ay = 0.f, az = 0.f, aw = 0.f;
    float bx = 0.f, by = 0.f, bz = 0.f, bw = 0.f;
    int e = start + g;
    for (; e + 4 < end; e += 8) {
        int s0 = csrSrc[e];
        int s1 = csrSrc[e + 4];
        uint2 q0 = H2[(long)s0 * 16 + f];
        uint2 q1 = H2[(long)s1 * 16 + f];
        ax += blo(q0.x); ay += bhi(q0.x); az += blo(q0.y); aw += bhi(q0.y);
        bx += blo(q1.x); by += bhi(q1.x); bz += blo(q1.y); bw += bhi(q1.y);
    }
    if (e < end) {
        uint2 q0 = H2[(long)csrSrc[e] * 16 + f];
        ax += blo(q0.x); ay += bhi(q0.x); az += blo(q0.y); aw += bhi(q0.y);
    }
    ax += bx; ay += by; az += bz; aw += bw;
    // reduce the 4 edge slots (xor on g bits 4,5)
    ax += __shfl_xor(ax, 16); ay += __shfl_xor(ay, 16);
    az += __shfl_xor(az, 16); aw += __shfl_xor(aw, 16);
    ax += __shfl_xor(ax, 32); ay += __shfl_xor(ay, 32);
    az += __shfl_xor(az, 32); aw += __shfl_xor(aw, 32);
    float di = dinv[node];
    uint2 qs = H2[(long)node * 16 + f];
    float4 bb = bias4[f];
    float vx = fmaxf((ax + blo(qs.x)) * di + bb.x, 0.f);
    float vy = fmaxf((ay + bhi(qs.x)) * di + bb.y, 0.f);
    float vz = fmaxf((az + blo(qs.y)) * di + bb.z, 0.f);
    float vw = fmaxf((aw + bhi(qs.y)) * di + bb.w, 0.f);
    if (doLN) {
        float s = vx + vy + vz + vw;
        s += __shfl_xor(s, 1); s += __shfl_xor(s, 2);
        s += __shfl_xor(s, 4); s += __shfl_xor(s, 8);
        float mu = s * (1.f / 64.f);
        vx -= mu; vy -= mu; vz -= mu; vw -= mu;
        float vs = vx * vx + vy * vy + vz * vz + vw * vw;
        vs += __shfl_xor(vs, 1); vs += __shfl_xor(vs, 2);
        vs += __shfl_xor(vs, 4); vs += __shfl_xor(vs, 8);
        float inv = rsqrtf(vs * (1.f / 64.f) + LN_EPS);
        float4 gg = g4[f];
        float4 tt = beta4[f];
        vx = vx * inv * gg.x + tt.x;
        vy = vy * inv * gg.y + tt.y;
        vz = vz * inv * gg.z + tt.z;
        vw = vw * inv * gg.w + tt.w;
    }
    if (g == 0) OUT4[(long)node * 16 + f] = make_float4(vx, vy, vz, vw);
}

// ---------------------------------------------------------------- dense MLP head, R3-exact one-shot shape
// 25000 blocks, 4 nodes/block, NO grid-stride, NO launch_bounds (measured clean in R3).
__global__ void mlp_k(const float* __restrict__ Hin, const float* __restrict__ W0,
                      const float* __restrict__ b0, const float* __restrict__ W1,
                      const float* __restrict__ b1, float* __restrict__ OUT) {
    __shared__ float sW0[64 * 64];
    __shared__ float sW1[64 * DOUT];
    __shared__ float sT[4 * 64];
    int tid = threadIdx.x;
    for (int i = tid; i < 64 * 64; i += 256) sW0[i] = W0[i];
    for (int i = tid; i < 64 * DOUT; i += 256) sW1[i] = W1[i];
    int w = tid >> 6, lane = tid & 63;
    int node = blockIdx.x * 4 + w;  // grid exactly NN/4
    float hv = Hin[(long)node * 64 + lane];
    __syncthreads();
    sT[w * 64 + lane] = hv;
    __syncthreads();
    float t = b0[lane];
#pragma unroll
    for (int k = 0; k < 64; ++k) t = fmaf(sT[w * 64 + k], sW0[k * 64 + lane], t);
    int li = (lane < DOUT) ? lane : 0;
    float o = b1[li];
#pragma unroll
    for (int k = 0; k < 64; ++k) o = fmaf(__shfl(t, k), sW1[k * DOUT + li], o);
    if (lane < DOUT) OUT[(long)node * DOUT + lane] = o;
}

// ----------------------------------------------------------------
extern "C" void kernel_launch(void* const* d_in, const int* in_sizes, int n_in,
                              void* d_out, int out_size, void* d_ws, size_t ws_size,
                              hipStream_t stream) {
    const float* x    = (const float*)d_in[0];
    const int*   ei   = (const int*)d_in[1];
    const int*   srcI = ei;
    const int*   dstI = ei + EE;
    const float* W0   = (const float*)d_in[2];
    const float* b0   = (const float*)d_in[3];
    const float* W1   = (const float*)d_in[4];
    const float* b1   = (const float*)d_in[5];
    const float* W2   = (const float*)d_in[6];
    const float* b2   = (const float*)d_in[7];
    const float* ln0g = (const float*)d_in[8];
    const float* ln0b = (const float*)d_in[9];
    const float* ln1g = (const float*)d_in[10];
    const float* ln1b = (const float*)d_in[11];
    const float* mpW0 = (const float*)d_in[12];
    const float* mpb0 = (const float*)d_in[13];
    const float* mpW1 = (const float*)d_in[14];
    const float* mpb1 = (const float*)d_in[15];
    float* out = (float*)d_out;

    char* ws = (char*)d_ws;
    float*    dinv   = (float*)   (ws + 0);
    int*      degI   = (int*)     (ws + 512l * 1024);
    int*      cursor = (int*)     (ws + 1024l * 1024);
    int*      bsum   = (int*)     (ws + 1536l * 1024);
    int*      csrSrc = (int*)     (ws + 2048l * 1024);          // 6.4 MB
    unsigned* bufA   = (unsigned*)(ws + 9l * 1024 * 1024);      // bf16 H'  12.8 MB
    float*    bufB   = (float*)   (ws + 23l * 1024 * 1024);     // f32 hidden 25.6 MB

    const int edgeBlocks = (EE + 255) / 256;
    const int aggBlocks  = NN / 4;  // 25000 exact

    hipMemsetAsync(degI, 0, NN * sizeof(int), stream);
    hist_k<<<edgeBlocks, 256, 0, stream>>>(dstI, degI);
    dinv_k<<<NB, 256, 0, stream>>>(degI, dinv);
    scan1_k<<<NB, 256, 0, stream>>>(degI, cursor, bsum);
    scan2_k<<<1, 512, 0, stream>>>(bsum);
    scan3_k<<<NB, 256, 0, stream>>>(cursor, bsum);
    reorder_k<<<edgeBlocks, 256, 0, stream>>>(srcI, dstI, cursor, csrSrc);

    // layer 0
    gemm_k<128><<<2048, 256, 0, stream>>>(x, W0, dinv, bufA);
    agg_k<<<aggBlocks, 256, 0, stream>>>(cursor, degI, csrSrc, dinv, (const uint2*)bufA,
                                         (const float4*)b0, (const float4*)ln0g,
                                         (const float4*)ln0b, (float4*)bufB, 1);
    // layer 1
    gemm_k<64><<<2048, 256, 0, stream>>>(bufB, W1, dinv, bufA);
    agg_k<<<aggBlocks, 256, 0, stream>>>(cursor, degI, csrSrc, dinv, (const uint2*)bufA,
                                         (const float4*)b1, (const float4*)ln1g,
                                         (const float4*)ln1b, (float4*)bufB, 1);
    // layer 2 (no LN) then dense MLP head
    gemm_k<64><<<2048, 256, 0, stream>>>(bufB, W2, dinv, bufA);
    agg_k<<<aggBlocks, 256, 0, stream>>>(cursor, degI, csrSrc, dinv, (const uint2*)bufA,
                                         (const float4*)b2, (const float4*)ln0g,
                                         (const float4*)ln0b, (float4*)bufB, 0);
    mlp_k<<<aggBlocks, 256, 0, stream>>>(bufB, mpW0, mpb0, mpW1, mpb1, out);
}

// Round 8
// 666.575 us; speedup vs baseline: 1.9887x; 1.4619x over previous
//
#include <hip/hip_runtime.h>
#include <hip/hip_bf16.h>

#define NN 100000
#define EE 1600000
#define DOUT 40
#define LN_EPS 1e-5f
#define NB 391  // (NN+255)/256

typedef __attribute__((ext_vector_type(8))) short short8;   // 8 bf16 = 4 VGPRs
typedef __attribute__((ext_vector_type(4))) float f32x4;    // MFMA acc

// ---------------------------------------------------------------- bf16 helpers (RNE pack)
__device__ __forceinline__ float blo(unsigned u) { return __uint_as_float(u << 16); }
__device__ __forceinline__ float bhi(unsigned u) { return __uint_as_float(u & 0xffff0000u); }
__device__ __forceinline__ unsigned bpack(float lo, float hi) {
    unsigned a = __float_as_uint(lo);
    unsigned b = __float_as_uint(hi);
    a = (a + 0x7fffu + ((a >> 16) & 1u)) >> 16;
    b = (b + 0x7fffu + ((b >> 16) & 1u)) & 0xffff0000u;
    return (a & 0xffffu) | b;
}

// ---------------------------------------------------------------- CSR build
__global__ void hist_k(const int* __restrict__ dst, int* __restrict__ degI) {
    int e = blockIdx.x * 256 + threadIdx.x;
    if (e < EE) atomicAdd(&degI[dst[e]], 1);
}

__global__ void dinv_k(const int* __restrict__ degI, float* __restrict__ dinv) {
    int n = blockIdx.x * 256 + threadIdx.x;
    if (n < NN) dinv[n] = rsqrtf((float)degI[n] + 1.0f);
}

__global__ void scan1_k(const int* __restrict__ degI, int* __restrict__ cursor,
                        int* __restrict__ bsum) {
    __shared__ int s[256];
    int tid = threadIdx.x;
    int i = blockIdx.x * 256 + tid;
    int v = (i < NN) ? degI[i] : 0;
    s[tid] = v;
    __syncthreads();
    for (int off = 1; off < 256; off <<= 1) {
        int t = (tid >= off) ? s[tid - off] : 0;
        __syncthreads();
        s[tid] += t;
        __syncthreads();
    }
    if (i < NN) cursor[i] = s[tid] - v;
    if (tid == 255) bsum[blockIdx.x] = s[255];
}

__global__ void scan2_k(int* __restrict__ bsum) {
    __shared__ int s[512];
    int tid = threadIdx.x;
    int v = (tid < NB) ? bsum[tid] : 0;
    s[tid] = v;
    __syncthreads();
    for (int off = 1; off < 512; off <<= 1) {
        int t = (tid >= off) ? s[tid - off] : 0;
        __syncthreads();
        s[tid] += t;
        __syncthreads();
    }
    if (tid < NB) bsum[tid] = s[tid] - v;
}

__global__ void scan3_k(int* __restrict__ cursor, const int* __restrict__ bsum) {
    int i = blockIdx.x * 256 + threadIdx.x;
    if (i < NN) cursor[i] += bsum[blockIdx.x];
}

__global__ void reorder_k(const int* __restrict__ src, const int* __restrict__ dst,
                          int* __restrict__ cursor, int* __restrict__ csrSrc) {
    int e = blockIdx.x * 256 + threadIdx.x;
    if (e < EE) {
        int pos = atomicAdd(&cursor[dst[e]], 1);
        csrSrc[pos] = src[e];
    }
}

// ---------------------------------------------------------------- MFMA GEMM: H' = bf16((X@W)*dinv)
// One-shot grid, 64 nodes/block (4 waves x 16 MFMA rows). A,W cast to bf16;
// mfma_f32_16x16x32_bf16: A[m=lane&15][k=q*8+j], B[k=q*8+j][n=lane&15],
// D col=lane&15, row=q*4+reg  (guide §3, HW-verified layouts).
template <int K>
__global__ __launch_bounds__(256, 2) void gemm_mfma(const float* __restrict__ X,
                                                    const float* __restrict__ W,
                                                    const float* __restrict__ dinv,
                                                    unsigned* __restrict__ H) {
    constexpr int C = K / 32;
    __shared__ unsigned short sW16[K * 66];  // row-major bf16, stride 66 (bank-conflict pad)
    __shared__ float sD[64 * 65];            // epilogue transpose, stride 65
    int tid = threadIdx.x;
    // stage W: f32 -> bf16, coalesced read
    for (int i = tid; i < K * 64; i += 256) {
        int k = i >> 6, n = i & 63;
        sW16[k * 66 + n] = (unsigned short)(bpack(W[i], 0.f) & 0xffffu);
    }
    __syncthreads();
    int wv = tid >> 6, lane = tid & 63;
    int q = lane >> 4, ln = lane & 15;
    // hoist B fragments into registers (once per kernel)
    short8 bfrag[C][4];
#pragma unroll
    for (int c = 0; c < C; ++c) {
#pragma unroll
        for (int t = 0; t < 4; ++t) {
            int kb = (c * 32 + q * 8) * 66 + t * 16 + ln;
            unsigned u0 = (unsigned)sW16[kb]       | ((unsigned)sW16[kb + 66]  << 16);
            unsigned u1 = (unsigned)sW16[kb + 132] | ((unsigned)sW16[kb + 198] << 16);
            unsigned u2 = (unsigned)sW16[kb + 264] | ((unsigned)sW16[kb + 330] << 16);
            unsigned u3 = (unsigned)sW16[kb + 396] | ((unsigned)sW16[kb + 462] << 16);
            uint4 u = make_uint4(u0, u1, u2, u3);
            bfrag[c][t] = __builtin_bit_cast(short8, u);
        }
    }
    int base = blockIdx.x * 64;
    int node = base + wv * 16 + ln;
    bool ok = node < NN;
    // A fragments: lane reads X[node][c*32 + q*8 .. +7], cvt to bf16
    short8 afrag[C];
#pragma unroll
    for (int c = 0; c < C; ++c) {
        float4 f0 = make_float4(0.f, 0.f, 0.f, 0.f);
        float4 f1 = make_float4(0.f, 0.f, 0.f, 0.f);
        if (ok) {
            const float4* xp = (const float4*)(X + (long)node * K + c * 32 + q * 8);
            f0 = xp[0];
            f1 = xp[1];
        }
        uint4 u;
        u.x = bpack(f0.x, f0.y);
        u.y = bpack(f0.z, f0.w);
        u.z = bpack(f1.x, f1.y);
        u.w = bpack(f1.z, f1.w);
        afrag[c] = __builtin_bit_cast(short8, u);
    }
#pragma unroll
    for (int t = 0; t < 4; ++t) {
        f32x4 acc = {0.f, 0.f, 0.f, 0.f};
#pragma unroll
        for (int c = 0; c < C; ++c)
            acc = __builtin_amdgcn_mfma_f32_16x16x32_bf16(afrag[c], bfrag[c][t], acc, 0, 0, 0);
#pragma unroll
        for (int r = 0; r < 4; ++r)
            sD[(wv * 16 + q * 4 + r) * 65 + t * 16 + ln] = acc[r];
    }
    __syncthreads();
    // pack: apply dinv, bf16x2 coalesced store
    for (int i = tid; i < 64 * 32; i += 256) {
        int row = i >> 5, c2 = i & 31;
        int nd = base + row;
        if (nd < NN) {
            float di = dinv[nd];
            float lo = sD[row * 65 + c2 * 2] * di;
            float hi = sD[row * 65 + c2 * 2 + 1] * di;
            H[nd * 32 + c2] = bpack(lo, hi);
        }
    }
}

// ---------------------------------------------------------------- aggregate + bias + relu + optional LN
// One-shot clean shape: wave/node; lane = g*16+f; uint2 (4 bf16) per lane.
__global__ __launch_bounds__(256, 4) void agg_k(
        const int* __restrict__ cursor, const int* __restrict__ degI,
        const int* __restrict__ csrSrc, const float* __restrict__ dinv,
        const uint2* __restrict__ H2, const float4* __restrict__ bias4,
        const float4* __restrict__ g4, const float4* __restrict__ beta4,
        float4* __restrict__ OUT4, int doLN) {
    int tid = threadIdx.x;
    int w = tid >> 6, lane = tid & 63;
    int g = lane >> 4;
    int f = lane & 15;
    int node = blockIdx.x * 4 + w;
    int end = cursor[node];
    int start = end - degI[node];
    float ax = 0.f, ay = 0.f, az = 0.f, aw = 0.f;
    float bx = 0.f, by = 0.f, bz = 0.f, bw = 0.f;
    int e = start + g;
    for (; e + 4 < end; e += 8) {
        int s0 = csrSrc[e];
        int s1 = csrSrc[e + 4];
        uint2 q0 = H2[(long)s0 * 16 + f];
        uint2 q1 = H2[(long)s1 * 16 + f];
        ax += blo(q0.x); ay += bhi(q0.x); az += blo(q0.y); aw += bhi(q0.y);
        bx += blo(q1.x); by += bhi(q1.x); bz += blo(q1.y); bw += bhi(q1.y);
    }
    if (e < end) {
        uint2 q0 = H2[(long)csrSrc[e] * 16 + f];
        ax += blo(q0.x); ay += bhi(q0.x); az += blo(q0.y); aw += bhi(q0.y);
    }
    ax += bx; ay += by; az += bz; aw += bw;
    ax += __shfl_xor(ax, 16); ay += __shfl_xor(ay, 16);
    az += __shfl_xor(az, 16); aw += __shfl_xor(aw, 16);
    ax += __shfl_xor(ax, 32); ay += __shfl_xor(ay, 32);
    az += __shfl_xor(az, 32); aw += __shfl_xor(aw, 32);
    float di = dinv[node];
    uint2 qs = H2[(long)node * 16 + f];
    float4 bb = bias4[f];
    float vx = fmaxf((ax + blo(qs.x)) * di + bb.x, 0.f);
    float vy = fmaxf((ay + bhi(qs.x)) * di + bb.y, 0.f);
    float vz = fmaxf((az + blo(qs.y)) * di + bb.z, 0.f);
    float vw = fmaxf((aw + bhi(qs.y)) * di + bb.w, 0.f);
    if (doLN) {
        float s = vx + vy + vz + vw;
        s += __shfl_xor(s, 1); s += __shfl_xor(s, 2);
        s += __shfl_xor(s, 4); s += __shfl_xor(s, 8);
        float mu = s * (1.f / 64.f);
        vx -= mu; vy -= mu; vz -= mu; vw -= mu;
        float vs = vx * vx + vy * vy + vz * vz + vw * vw;
        vs += __shfl_xor(vs, 1); vs += __shfl_xor(vs, 2);
        vs += __shfl_xor(vs, 4); vs += __shfl_xor(vs, 8);
        float inv = rsqrtf(vs * (1.f / 64.f) + LN_EPS);
        float4 gg = g4[f];
        float4 tt = beta4[f];
        vx = vx * inv * gg.x + tt.x;
        vy = vy * inv * gg.y + tt.y;
        vz = vz * inv * gg.z + tt.z;
        vw = vw * inv * gg.w + tt.w;
    }
    if (g == 0) OUT4[(long)node * 16 + f] = make_float4(vx, vy, vz, vw);
}

// ---------------------------------------------------------------- dense MLP head, one-shot clean shape
__global__ void mlp_k(const float* __restrict__ Hin, const float* __restrict__ W0,
                      const float* __restrict__ b0, const float* __restrict__ W1,
                      const float* __restrict__ b1, float* __restrict__ OUT) {
    __shared__ float sW0[64 * 64];
    __shared__ float sW1[64 * DOUT];
    __shared__ float sT[4 * 64];
    int tid = threadIdx.x;
    for (int i = tid; i < 64 * 64; i += 256) sW0[i] = W0[i];
    for (int i = tid; i < 64 * DOUT; i += 256) sW1[i] = W1[i];
    int w = tid >> 6, lane = tid & 63;
    int node = blockIdx.x * 4 + w;
    float hv = Hin[(long)node * 64 + lane];
    __syncthreads();
    sT[w * 64 + lane] = hv;
    __syncthreads();
    float t = b0[lane];
#pragma unroll
    for (int k = 0; k < 64; ++k) t = fmaf(sT[w * 64 + k], sW0[k * 64 + lane], t);
    int li = (lane < DOUT) ? lane : 0;
    float o = b1[li];
#pragma unroll
    for (int k = 0; k < 64; ++k) o = fmaf(__shfl(t, k), sW1[k * DOUT + li], o);
    if (lane < DOUT) OUT[(long)node * DOUT + lane] = o;
}

// ----------------------------------------------------------------
extern "C" void kernel_launch(void* const* d_in, const int* in_sizes, int n_in,
                              void* d_out, int out_size, void* d_ws, size_t ws_size,
                              hipStream_t stream) {
    const float* x    = (const float*)d_in[0];
    const int*   ei   = (const int*)d_in[1];
    const int*   srcI = ei;
    const int*   dstI = ei + EE;
    const float* W0   = (const float*)d_in[2];
    const float* b0   = (const float*)d_in[3];
    const float* W1   = (const float*)d_in[4];
    const float* b1   = (const float*)d_in[5];
    const float* W2   = (const float*)d_in[6];
    const float* b2   = (const float*)d_in[7];
    const float* ln0g = (const float*)d_in[8];
    const float* ln0b = (const float*)d_in[9];
    const float* ln1g = (const float*)d_in[10];
    const float* ln1b = (const float*)d_in[11];
    const float* mpW0 = (const float*)d_in[12];
    const float* mpb0 = (const float*)d_in[13];
    const float* mpW1 = (const float*)d_in[14];
    const float* mpb1 = (const float*)d_in[15];
    float* out = (float*)d_out;

    char* ws = (char*)d_ws;
    float*    dinv   = (float*)   (ws + 0);
    int*      degI   = (int*)     (ws + 512l * 1024);
    int*      cursor = (int*)     (ws + 1024l * 1024);
    int*      bsum   = (int*)     (ws + 1536l * 1024);
    int*      csrSrc = (int*)     (ws + 2048l * 1024);          // 6.4 MB
    unsigned* bufA   = (unsigned*)(ws + 9l * 1024 * 1024);      // bf16 H'  12.8 MB
    float*    bufB   = (float*)   (ws + 23l * 1024 * 1024);     // f32 hidden 25.6 MB

    const int edgeBlocks = (EE + 255) / 256;
    const int aggBlocks  = NN / 4;            // 25000 exact
    const int gemmBlocks = (NN + 63) / 64;    // 1563, one-shot

    hipMemsetAsync(degI, 0, NN * sizeof(int), stream);
    hist_k<<<edgeBlocks, 256, 0, stream>>>(dstI, degI);
    dinv_k<<<NB, 256, 0, stream>>>(degI, dinv);
    scan1_k<<<NB, 256, 0, stream>>>(degI, cursor, bsum);
    scan2_k<<<1, 512, 0, stream>>>(bsum);
    scan3_k<<<NB, 256, 0, stream>>>(cursor, bsum);
    reorder_k<<<edgeBlocks, 256, 0, stream>>>(srcI, dstI, cursor, csrSrc);

    // layer 0
    gemm_mfma<128><<<gemmBlocks, 256, 0, stream>>>(x, W0, dinv, bufA);
    agg_k<<<aggBlocks, 256, 0, stream>>>(cursor, degI, csrSrc, dinv, (const uint2*)bufA,
                                         (const float4*)b0, (const float4*)ln0g,
                                         (const float4*)ln0b, (float4*)bufB, 1);
    // layer 1
    gemm_mfma<64><<<gemmBlocks, 256, 0, stream>>>(bufB, W1, dinv, bufA);
    agg_k<<<aggBlocks, 256, 0, stream>>>(cursor, degI, csrSrc, dinv, (const uint2*)bufA,
                                         (const float4*)b1, (const float4*)ln1g,
                                         (const float4*)ln1b, (float4*)bufB, 1);
    // layer 2 (no LN) then dense MLP head
    gemm_mfma<64><<<gemmBlocks, 256, 0, stream>>>(bufB, W2, dinv, bufA);
    agg_k<<<aggBlocks, 256, 0, stream>>>(cursor, degI, csrSrc, dinv, (const uint2*)bufA,
                                         (const float4*)b2, (const float4*)ln0g,
                                         (const float4*)ln0b, (float4*)bufB, 0);
    mlp_k<<<aggBlocks, 256, 0, stream>>>(bufB, mpW0, mpb0, mpW1, mpb1, out);
}

// Round 9
// 549.973 us; speedup vs baseline: 2.4103x; 1.2120x over previous
//
#include <hip/hip_runtime.h>
#include <hip/hip_bf16.h>

#define NN 100000
#define EE 1600000
#define DOUT 40
#define LN_EPS 1e-5f
#define NB 391  // (NN+255)/256

typedef __attribute__((ext_vector_type(8))) short short8;   // 8 bf16 = 4 VGPRs
typedef __attribute__((ext_vector_type(4))) float f32x4;    // MFMA acc

// ---------------------------------------------------------------- bf16 helpers (RNE pack)
__device__ __forceinline__ float blo(unsigned u) { return __uint_as_float(u << 16); }
__device__ __forceinline__ float bhi(unsigned u) { return __uint_as_float(u & 0xffff0000u); }
__device__ __forceinline__ unsigned bpack(float lo, float hi) {
    unsigned a = __float_as_uint(lo);
    unsigned b = __float_as_uint(hi);
    a = (a + 0x7fffu + ((a >> 16) & 1u)) >> 16;
    b = (b + 0x7fffu + ((b >> 16) & 1u)) & 0xffff0000u;
    return (a & 0xffffu) | b;
}

// ---------------------------------------------------------------- CSR build
__global__ void hist_k(const int* __restrict__ dst, int* __restrict__ degI) {
    int e = blockIdx.x * 256 + threadIdx.x;
    if (e < EE) atomicAdd(&degI[dst[e]], 1);
}

__global__ void dinv_k(const int* __restrict__ degI, float* __restrict__ dinv) {
    int n = blockIdx.x * 256 + threadIdx.x;
    if (n < NN) dinv[n] = rsqrtf((float)degI[n] + 1.0f);
}

__global__ void scan1_k(const int* __restrict__ degI, int* __restrict__ cursor,
                        int* __restrict__ bsum) {
    __shared__ int s[256];
    int tid = threadIdx.x;
    int i = blockIdx.x * 256 + tid;
    int v = (i < NN) ? degI[i] : 0;
    s[tid] = v;
    __syncthreads();
    for (int off = 1; off < 256; off <<= 1) {
        int t = (tid >= off) ? s[tid - off] : 0;
        __syncthreads();
        s[tid] += t;
        __syncthreads();
    }
    if (i < NN) cursor[i] = s[tid] - v;
    if (tid == 255) bsum[blockIdx.x] = s[255];
}

__global__ void scan2_k(int* __restrict__ bsum) {
    __shared__ int s[512];
    int tid = threadIdx.x;
    int v = (tid < NB) ? bsum[tid] : 0;
    s[tid] = v;
    __syncthreads();
    for (int off = 1; off < 512; off <<= 1) {
        int t = (tid >= off) ? s[tid - off] : 0;
        __syncthreads();
        s[tid] += t;
        __syncthreads();
    }
    if (tid < NB) bsum[tid] = s[tid] - v;
}

__global__ void scan3_k(int* __restrict__ cursor, const int* __restrict__ bsum) {
    int i = blockIdx.x * 256 + threadIdx.x;
    if (i < NN) cursor[i] += bsum[blockIdx.x];
}

__global__ void reorder_k(const int* __restrict__ src, const int* __restrict__ dst,
                          int* __restrict__ cursor, int* __restrict__ csrSrc) {
    int e = blockIdx.x * 256 + threadIdx.x;
    if (e < EE) {
        int pos = atomicAdd(&cursor[dst[e]], 1);
        csrSrc[pos] = src[e];
    }
}

// ---------------------------------------------------------------- MFMA GEMM: H' = bf16((X@W)*dinv)
template <int K>
__global__ __launch_bounds__(256, 2) void gemm_mfma(const float* __restrict__ X,
                                                    const float* __restrict__ W,
                                                    const float* __restrict__ dinv,
                                                    unsigned* __restrict__ H) {
    constexpr int C = K / 32;
    __shared__ unsigned short sW16[K * 66];  // row-major bf16, stride 66
    __shared__ float sD[64 * 65];            // epilogue transpose, stride 65
    int tid = threadIdx.x;
    for (int i = tid; i < K * 64; i += 256) {
        int k = i >> 6, n = i & 63;
        sW16[k * 66 + n] = (unsigned short)(bpack(W[i], 0.f) & 0xffffu);
    }
    __syncthreads();
    int wv = tid >> 6, lane = tid & 63;
    int q = lane >> 4, ln = lane & 15;
    short8 bfrag[C][4];
#pragma unroll
    for (int c = 0; c < C; ++c) {
#pragma unroll
        for (int t = 0; t < 4; ++t) {
            int kb = (c * 32 + q * 8) * 66 + t * 16 + ln;
            unsigned u0 = (unsigned)sW16[kb]       | ((unsigned)sW16[kb + 66]  << 16);
            unsigned u1 = (unsigned)sW16[kb + 132] | ((unsigned)sW16[kb + 198] << 16);
            unsigned u2 = (unsigned)sW16[kb + 264] | ((unsigned)sW16[kb + 330] << 16);
            unsigned u3 = (unsigned)sW16[kb + 396] | ((unsigned)sW16[kb + 462] << 16);
            uint4 u = make_uint4(u0, u1, u2, u3);
            bfrag[c][t] = __builtin_bit_cast(short8, u);
        }
    }
    int base = blockIdx.x * 64;
    int node = base + wv * 16 + ln;
    bool ok = node < NN;
    short8 afrag[C];
#pragma unroll
    for (int c = 0; c < C; ++c) {
        float4 f0 = make_float4(0.f, 0.f, 0.f, 0.f);
        float4 f1 = make_float4(0.f, 0.f, 0.f, 0.f);
        if (ok) {
            const float4* xp = (const float4*)(X + (long)node * K + c * 32 + q * 8);
            f0 = xp[0];
            f1 = xp[1];
        }
        uint4 u;
        u.x = bpack(f0.x, f0.y);
        u.y = bpack(f0.z, f0.w);
        u.z = bpack(f1.x, f1.y);
        u.w = bpack(f1.z, f1.w);
        afrag[c] = __builtin_bit_cast(short8, u);
    }
#pragma unroll
    for (int t = 0; t < 4; ++t) {
        f32x4 acc = {0.f, 0.f, 0.f, 0.f};
#pragma unroll
        for (int c = 0; c < C; ++c)
            acc = __builtin_amdgcn_mfma_f32_16x16x32_bf16(afrag[c], bfrag[c][t], acc, 0, 0, 0);
#pragma unroll
        for (int r = 0; r < 4; ++r)
            sD[(wv * 16 + q * 4 + r) * 65 + t * 16 + ln] = acc[r];
    }
    __syncthreads();
    for (int i = tid; i < 64 * 32; i += 256) {
        int row = i >> 5, c2 = i & 31;
        int nd = base + row;
        if (nd < NN) {
            float di = dinv[nd];
            float lo = sD[row * 65 + c2 * 2] * di;
            float hi = sD[row * 65 + c2 * 2 + 1] * di;
            H[nd * 32 + c2] = bpack(lo, hi);
        }
    }
}

// ---------------------------------------------------------------- aggregate + bias + relu + optional LN
__global__ __launch_bounds__(256, 4) void agg_k(
        const int* __restrict__ cursor, const int* __restrict__ degI,
        const int* __restrict__ csrSrc, const float* __restrict__ dinv,
        const uint2* __restrict__ H2, const float4* __restrict__ bias4,
        const float4* __restrict__ g4, const float4* __restrict__ beta4,
        float4* __restrict__ OUT4, int doLN) {
    int tid = threadIdx.x;
    int w = tid >> 6, lane = tid & 63;
    int g = lane >> 4;
    int f = lane & 15;
    int node = blockIdx.x * 4 + w;
    int end = cursor[node];
    int start = end - degI[node];
    float ax = 0.f, ay = 0.f, az = 0.f, aw = 0.f;
    float bx = 0.f, by = 0.f, bz = 0.f, bw = 0.f;
    int e = start + g;
    for (; e + 4 < end; e += 8) {
        int s0 = csrSrc[e];
        int s1 = csrSrc[e + 4];
        uint2 q0 = H2[(long)s0 * 16 + f];
        uint2 q1 = H2[(long)s1 * 16 + f];
        ax += blo(q0.x); ay += bhi(q0.x); az += blo(q0.y); aw += bhi(q0.y);
        bx += blo(q1.x); by += bhi(q1.x); bz += blo(q1.y); bw += bhi(q1.y);
    }
    if (e < end) {
        uint2 q0 = H2[(long)csrSrc[e] * 16 + f];
        ax += blo(q0.x); ay += bhi(q0.x); az += blo(q0.y); aw += bhi(q0.y);
    }
    ax += bx; ay += by; az += bz; aw += bw;
    ax += __shfl_xor(ax, 16); ay += __shfl_xor(ay, 16);
    az += __shfl_xor(az, 16); aw += __shfl_xor(aw, 16);
    ax += __shfl_xor(ax, 32); ay += __shfl_xor(ay, 32);
    az += __shfl_xor(az, 32); aw += __shfl_xor(aw, 32);
    float di = dinv[node];
    uint2 qs = H2[(long)node * 16 + f];
    float4 bb = bias4[f];
    float vx = fmaxf((ax + blo(qs.x)) * di + bb.x, 0.f);
    float vy = fmaxf((ay + bhi(qs.x)) * di + bb.y, 0.f);
    float vz = fmaxf((az + blo(qs.y)) * di + bb.z, 0.f);
    float vw = fmaxf((aw + bhi(qs.y)) * di + bb.w, 0.f);
    if (doLN) {
        float s = vx + vy + vz + vw;
        s += __shfl_xor(s, 1); s += __shfl_xor(s, 2);
        s += __shfl_xor(s, 4); s += __shfl_xor(s, 8);
        float mu = s * (1.f / 64.f);
        vx -= mu; vy -= mu; vz -= mu; vw -= mu;
        float vs = vx * vx + vy * vy + vz * vz + vw * vw;
        vs += __shfl_xor(vs, 1); vs += __shfl_xor(vs, 2);
        vs += __shfl_xor(vs, 4); vs += __shfl_xor(vs, 8);
        float inv = rsqrtf(vs * (1.f / 64.f) + LN_EPS);
        float4 gg = g4[f];
        float4 tt = beta4[f];
        vx = vx * inv * gg.x + tt.x;
        vy = vy * inv * gg.y + tt.y;
        vz = vz * inv * gg.z + tt.z;
        vw = vw * inv * gg.w + tt.w;
    }
    if (g == 0) OUT4[(long)node * 16 + f] = make_float4(vx, vy, vz, vw);
}

// ---------------------------------------------------------------- fuse the two head linears (no act between):
// Wf = W0@W1 [64x48 padded], bf = b0@W1 + b1 [48]
__global__ void fuse_k(const float* __restrict__ W0, const float* __restrict__ b0,
                       const float* __restrict__ W1, const float* __restrict__ b1,
                       float* __restrict__ Wf, float* __restrict__ bf) {
    int tid = threadIdx.x;
    for (int i = tid; i < 64 * 48; i += 256) {
        int k = i / 48, n = i % 48;
        float acc = 0.f;
        if (n < DOUT) {
            for (int j = 0; j < 64; ++j) acc = fmaf(W0[k * 64 + j], W1[j * DOUT + n], acc);
        }
        Wf[i] = acc;
    }
    for (int n = tid; n < 48; n += 256) {
        float acc = 0.f;
        if (n < DOUT) {
            acc = b1[n];
            for (int j = 0; j < 64; ++j) acc = fmaf(b0[j], W1[j * DOUT + n], acc);
        }
        bf[n] = acc;
    }
}

// ---------------------------------------------------------------- MLP head via MFMA: OUT = Hin @ Wf + bf
__global__ __launch_bounds__(256, 2) void mlp_mfma(const float* __restrict__ Hin,
                                                   const float* __restrict__ Wf,
                                                   const float* __restrict__ bf,
                                                   float* __restrict__ OUT) {
    __shared__ unsigned short sW16[64 * 50];  // 64 K-rows x 48 cols, stride 50
    int tid = threadIdx.x;
    for (int i = tid; i < 64 * 48; i += 256) {
        int k = i / 48, n = i % 48;
        sW16[k * 50 + n] = (unsigned short)(bpack(Wf[i], 0.f) & 0xffffu);
    }
    __syncthreads();
    int wv = tid >> 6, lane = tid & 63;
    int q = lane >> 4, ln = lane & 15;
    short8 bfrag[2][3];
#pragma unroll
    for (int c = 0; c < 2; ++c) {
#pragma unroll
        for (int t = 0; t < 3; ++t) {
            int kb = (c * 32 + q * 8) * 50 + t * 16 + ln;
            unsigned u0 = (unsigned)sW16[kb]       | ((unsigned)sW16[kb + 50]  << 16);
            unsigned u1 = (unsigned)sW16[kb + 100] | ((unsigned)sW16[kb + 150] << 16);
            unsigned u2 = (unsigned)sW16[kb + 200] | ((unsigned)sW16[kb + 250] << 16);
            unsigned u3 = (unsigned)sW16[kb + 300] | ((unsigned)sW16[kb + 350] << 16);
            uint4 u = make_uint4(u0, u1, u2, u3);
            bfrag[c][t] = __builtin_bit_cast(short8, u);
        }
    }
    int base = blockIdx.x * 64;
    int node = base + wv * 16 + ln;
    bool ok = node < NN;
    short8 afrag[2];
#pragma unroll
    for (int c = 0; c < 2; ++c) {
        float4 f0 = make_float4(0.f, 0.f, 0.f, 0.f);
        float4 f1 = make_float4(0.f, 0.f, 0.f, 0.f);
        if (ok) {
            const float4* xp = (const float4*)(Hin + (long)node * 64 + c * 32 + q * 8);
            f0 = xp[0];
            f1 = xp[1];
        }
        uint4 u;
        u.x = bpack(f0.x, f0.y);
        u.y = bpack(f0.z, f0.w);
        u.z = bpack(f1.x, f1.y);
        u.w = bpack(f1.z, f1.w);
        afrag[c] = __builtin_bit_cast(short8, u);
    }
#pragma unroll
    for (int t = 0; t < 3; ++t) {
        f32x4 acc = {0.f, 0.f, 0.f, 0.f};
        acc = __builtin_amdgcn_mfma_f32_16x16x32_bf16(afrag[0], bfrag[0][t], acc, 0, 0, 0);
        acc = __builtin_amdgcn_mfma_f32_16x16x32_bf16(afrag[1], bfrag[1][t], acc, 0, 0, 0);
        int col = t * 16 + ln;
        if (col < DOUT) {
            float bv = bf[col];
#pragma unroll
            for (int r = 0; r < 4; ++r) {
                int nd = base + wv * 16 + q * 4 + r;
                if (nd < NN) OUT[(long)nd * DOUT + col] = acc[r] + bv;
            }
        }
    }
}

// ----------------------------------------------------------------
extern "C" void kernel_launch(void* const* d_in, const int* in_sizes, int n_in,
                              void* d_out, int out_size, void* d_ws, size_t ws_size,
                              hipStream_t stream) {
    const float* x    = (const float*)d_in[0];
    const int*   ei   = (const int*)d_in[1];
    const int*   srcI = ei;
    const int*   dstI = ei + EE;
    const float* W0   = (const float*)d_in[2];
    const float* b0   = (const float*)d_in[3];
    const float* W1   = (const float*)d_in[4];
    const float* b1   = (const float*)d_in[5];
    const float* W2   = (const float*)d_in[6];
    const float* b2   = (const float*)d_in[7];
    const float* ln0g = (const float*)d_in[8];
    const float* ln0b = (const float*)d_in[9];
    const float* ln1g = (const float*)d_in[10];
    const float* ln1b = (const float*)d_in[11];
    const float* mpW0 = (const float*)d_in[12];
    const float* mpb0 = (const float*)d_in[13];
    const float* mpW1 = (const float*)d_in[14];
    const float* mpb1 = (const float*)d_in[15];
    float* out = (float*)d_out;

    char* ws = (char*)d_ws;
    float*    dinv   = (float*)   (ws + 0);
    int*      degI   = (int*)     (ws + 512l * 1024);
    int*      cursor = (int*)     (ws + 1024l * 1024);
    int*      bsum   = (int*)     (ws + 1536l * 1024);
    float*    Wf     = (float*)   (ws + 1792l * 1024);          // 64x48 f32
    float*    bfv    = (float*)   (ws + 1984l * 1024);          // 48 f32
    int*      csrSrc = (int*)     (ws + 2048l * 1024);          // 6.4 MB
    unsigned* bufA   = (unsigned*)(ws + 9l * 1024 * 1024);      // bf16 H'  12.8 MB
    float*    bufB   = (float*)   (ws + 23l * 1024 * 1024);     // f32 hidden 25.6 MB

    const int edgeBlocks = (EE + 255) / 256;
    const int aggBlocks  = NN / 4;            // 25000 exact
    const int gemmBlocks = (NN + 63) / 64;    // 1563, one-shot

    hipMemsetAsync(degI, 0, NN * sizeof(int), stream);
    hist_k<<<edgeBlocks, 256, 0, stream>>>(dstI, degI);
    dinv_k<<<NB, 256, 0, stream>>>(degI, dinv);
    scan1_k<<<NB, 256, 0, stream>>>(degI, cursor, bsum);
    scan2_k<<<1, 512, 0, stream>>>(bsum);
    scan3_k<<<NB, 256, 0, stream>>>(cursor, bsum);
    reorder_k<<<edgeBlocks, 256, 0, stream>>>(srcI, dstI, cursor, csrSrc);
    fuse_k<<<1, 256, 0, stream>>>(mpW0, mpb0, mpW1, mpb1, Wf, bfv);

    // layer 0
    gemm_mfma<128><<<gemmBlocks, 256, 0, stream>>>(x, W0, dinv, bufA);
    agg_k<<<aggBlocks, 256, 0, stream>>>(cursor, degI, csrSrc, dinv, (const uint2*)bufA,
                                         (const float4*)b0, (const float4*)ln0g,
                                         (const float4*)ln0b, (float4*)bufB, 1);
    // layer 1
    gemm_mfma<64><<<gemmBlocks, 256, 0, stream>>>(bufB, W1, dinv, bufA);
    agg_k<<<aggBlocks, 256, 0, stream>>>(cursor, degI, csrSrc, dinv, (const uint2*)bufA,
                                         (const float4*)b1, (const float4*)ln1g,
                                         (const float4*)ln1b, (float4*)bufB, 1);
    // layer 2 (no LN) then fused MLP head via MFMA
    gemm_mfma<64><<<gemmBlocks, 256, 0, stream>>>(bufB, W2, dinv, bufA);
    agg_k<<<aggBlocks, 256, 0, stream>>>(cursor, degI, csrSrc, dinv, (const uint2*)bufA,
                                         (const float4*)b2, (const float4*)ln0g,
                                         (const float4*)ln0b, (float4*)bufB, 0);
    mlp_mfma<<<gemmBlocks, 256, 0, stream>>>(bufB, Wf, bfv, out);
}